// Round 1
// baseline (346.093 us; speedup 1.0000x reference)
//
#include <hip/hip_runtime.h>

// out[(b*N + n)*D + c][s] = q[b][s][c] * w[n][c]
// B=8, S=2048, D=256, N=20, fp32 in/out.
// Memory-bound: ~336 MB writes + ~17 MB reads. LDS tile transpose so both
// global reads (along c) and global writes (along s) are float4-coalesced.

namespace {
constexpr int kB = 8;
constexpr int kS = 2048;
constexpr int kD = 256;
constexpr int kN = 20;
constexpr int TS = 64;           // s-tile
constexpr int TC = 64;           // c-tile
constexpr int PAD_TS = TS + 4;   // row stride 68 floats = 272 B: keeps float4
                                 // LDS reads 16B-aligned, breaks pow2 banking
}

__global__ __launch_bounds__(256)
void frw_kernel(const float* __restrict__ q, const float* __restrict__ w,
                float* __restrict__ out) {
  const int s0 = blockIdx.x * TS;
  const int c0 = blockIdx.y * TC;
  const int b  = blockIdx.z;
  const int t  = threadIdx.x;

  __shared__ float tile[TC][PAD_TS];  // [c][s]
  __shared__ float ws[kN][TC];

  // Preload the 20x64 slice of w for this c-tile (1280 floats, 5 per thread).
  for (int i = t; i < kN * TC; i += 256) {
    const int n  = i / TC;
    const int cc = i % TC;
    ws[n][cc] = w[n * kD + c0 + cc];
  }

  const int lane16 = t & 15;
  const int grp16  = t >> 4;

  // Load 64(s) x 64(c) tile of q, coalesced float4 along c (innermost dim of
  // q), scatter transposed into LDS as [c][s].
  {
    const int cvec = lane16 * 4;
    for (int k = 0; k < 4; ++k) {
      const int srow = grp16 + k * 16;
      const float4 v = *reinterpret_cast<const float4*>(
          &q[((size_t)b * kS + (size_t)(s0 + srow)) * kD + (c0 + cvec)]);
      tile[cvec + 0][srow] = v.x;
      tile[cvec + 1][srow] = v.y;
      tile[cvec + 2][srow] = v.z;
      tile[cvec + 3][srow] = v.w;
    }
  }
  __syncthreads();

  // Write phase: thread handles 4 c-rows; per row one float4 of s, scaled by
  // w[n][c] for each of the 20 classes. Per 16-lane group: 256 B contiguous
  // along s -> every 64B line fully written.
  const int svec = lane16 * 4;
  for (int k = 0; k < 4; ++k) {
    const int cc = grp16 + k * 16;
    const int c  = c0 + cc;
    const float4 v = *reinterpret_cast<const float4*>(&tile[cc][svec]);
    size_t idx = ((size_t)b * kN * kD + (size_t)c) * kS + (size_t)(s0 + svec);
    for (int n = 0; n < kN; ++n) {
      const float sc = ws[n][cc];
      float4 o;
      o.x = v.x * sc;
      o.y = v.y * sc;
      o.z = v.z * sc;
      o.w = v.w * sc;
      *reinterpret_cast<float4*>(&out[idx]) = o;
      idx += (size_t)kD * kS;
    }
  }
}

extern "C" void kernel_launch(void* const* d_in, const int* in_sizes, int n_in,
                              void* d_out, int out_size, void* d_ws, size_t ws_size,
                              hipStream_t stream) {
  const float* q = (const float*)d_in[0];  // (B, S, D)
  const float* w = (const float*)d_in[1];  // (N, D)
  float* out = (float*)d_out;              // (B*N, D, S)

  dim3 grid(kS / TS, kD / TC, kB);  // 32 x 4 x 8 = 1024 blocks
  frw_kernel<<<grid, 256, 0, stream>>>(q, w, out);
}

// Round 2
// 340.662 us; speedup vs baseline: 1.0159x; 1.0159x over previous
//
#include <hip/hip_runtime.h>

// out[(b*N + n)*D + c][s] = q[b][s][c] * w[n][c]
// B=8, S=2048, D=256, N=20, fp32 in/out.
// Write-bound: ~336 MB out + ~17 MB in. R1 (TS=64) wrote scattered 256 B
// fragments -> ~3 TB/s. R2: TS=512 so each (n,c) row gets a 2 KB contiguous
// write per block; LDS tile transpose keeps reads (along c) and writes
// (along s) float4-coalesced.

namespace {
constexpr int kB = 8;
constexpr int kS = 2048;
constexpr int kD = 256;
constexpr int kN = 20;
constexpr int TS = 512;          // s-tile: 2 KB contiguous per (n,c) row
constexpr int TC = 16;           // c-tile
constexpr int PTS = TS + 4;      // pad: row stride 516 floats breaks pow2
                                 // banking, keeps float4 LDS ops 16B-aligned
}

__global__ __launch_bounds__(256)
void frw_kernel(const float* __restrict__ q, const float* __restrict__ w,
                float* __restrict__ out) {
  const int s0 = blockIdx.x * TS;
  const int c0 = blockIdx.y * TC;
  const int b  = blockIdx.z;
  const int t  = threadIdx.x;

  __shared__ float tile[TC][PTS];  // [c][s]
  __shared__ float ws[kN][TC];

  // Preload 20x16 slice of w (320 floats).
  for (int i = t; i < kN * TC; i += 256) {
    const int n  = i / TC;
    const int cc = i % TC;
    ws[n][cc] = w[n * kD + c0 + cc];
  }

  // Load 512(s) x 16(c) tile of q: 4 lanes cover one s-row (64 B contiguous,
  // line-aligned), 256 threads cover 64 s-rows per pass, 8 passes.
  {
    const int lane4 = t & 3;
    const int srow  = t >> 2;        // 0..63
    const int cvec  = lane4 * 4;
#pragma unroll
    for (int k = 0; k < 8; ++k) {
      const int ss = srow + k * 64;
      const float4 v = *reinterpret_cast<const float4*>(
          &q[((size_t)b * kS + (size_t)(s0 + ss)) * kD + (c0 + cvec)]);
      tile[cvec + 0][ss] = v.x;   // 2-way LDS bank aliasing: free
      tile[cvec + 1][ss] = v.y;
      tile[cvec + 2][ss] = v.z;
      tile[cvec + 3][ss] = v.w;
    }
  }
  __syncthreads();

  // Write phase: 256 threads x float4 = 1024 floats = 2 full rows of 512 per
  // pass. Each wave writes 1 KB contiguous; a row pair = 2x 2 KB fragments.
  const int half = t >> 7;           // which row of the pair
  const int soff = (t & 127) * 4;    // 0..508
  for (int n = 0; n < kN; ++n) {
    const size_t base_bn = ((size_t)(b * kN + n)) * kD;
#pragma unroll
    for (int rg = 0; rg < TC / 2; ++rg) {
      const int r = rg * 2 + half;
      const float sc = ws[n][r];     // wave-uniform -> LDS broadcast
      const float4 v = *reinterpret_cast<const float4*>(&tile[r][soff]);
      float4 o;
      o.x = v.x * sc;
      o.y = v.y * sc;
      o.z = v.z * sc;
      o.w = v.w * sc;
      *reinterpret_cast<float4*>(
          &out[(base_bn + (size_t)(c0 + r)) * kS + (size_t)(s0 + soff)]) = o;
    }
  }
}

extern "C" void kernel_launch(void* const* d_in, const int* in_sizes, int n_in,
                              void* d_out, int out_size, void* d_ws, size_t ws_size,
                              hipStream_t stream) {
  const float* q = (const float*)d_in[0];  // (B, S, D)
  const float* w = (const float*)d_in[1];  // (N, D)
  float* out = (float*)d_out;              // (B*N, D, S)

  dim3 grid(kS / TS, kD / TC, kB);  // 4 x 16 x 8 = 512 blocks
  frw_kernel<<<grid, 256, 0, stream>>>(q, w, out);
}